// Round 16
// baseline (11184.034 us; speedup 1.0000x reference)
//
#include <hip/hip_runtime.h>

#define SLEN 512
#define BATCH 64
#define IDIM 256
#define HDIM 1024
#define ODIM 128
#define NBLK 256
#define NTHR 512
#define AGENT __HIP_MEMORY_SCOPE_AGENT
#define SLOTB 1605632ull   // bytes per rotation slot

typedef unsigned short ushortT;
typedef unsigned long long ull;
typedef __attribute__((ext_vector_type(8))) short short8;
typedef __attribute__((ext_vector_type(4))) float f32x4;

__device__ __forceinline__ ushortT f2bf(float f) {
  unsigned u = __float_as_uint(f);
  unsigned r = (u + 0x7FFFu + ((u >> 16) & 1u)) >> 16;
  return (ushortT)r;
}

__device__ __forceinline__ void pack2(const float* __restrict__ s, ushortT* d) {
  float4 a = *(const float4*)s;
  float4 b = *(const float4*)(s + 16);
  short8 v;
  v[0]=(short)f2bf(a.x); v[1]=(short)f2bf(a.y); v[2]=(short)f2bf(a.z); v[3]=(short)f2bf(a.w);
  v[4]=(short)f2bf(b.x); v[5]=(short)f2bf(b.y); v[6]=(short)f2bf(b.z); v[7]=(short)f2bf(b.w);
  *(short8*)d = v;
}

// write-through (agent) variant for cross-block global mirrors
__device__ __forceinline__ void pack2a(const float* __restrict__ s, ushortT* d) {
  float4 a = *(const float4*)s;
  float4 b = *(const float4*)(s + 16);
  ull lo = (ull)f2bf(a.x) | ((ull)f2bf(a.y) << 16) | ((ull)f2bf(a.z) << 32) | ((ull)f2bf(a.w) << 48);
  ull hi = (ull)f2bf(b.x) | ((ull)f2bf(b.y) << 16) | ((ull)f2bf(b.z) << 32) | ((ull)f2bf(b.w) << 48);
  __hip_atomic_store((ull*)d, lo, __ATOMIC_RELAXED, AGENT);
  __hip_atomic_store((ull*)(d + 4), hi, __ATOMIC_RELAXED, AGENT);
}

__device__ __forceinline__ void mir_store(ushortT* M, int row, int cL, float v) {
  int kt = cL >> 5, c5 = cL & 31;
  int h = c5 >> 4, g = (c5 >> 2) & 3, j = c5 & 3;
  int u = ((kt * 4 + (row >> 4)) * 64) + 16 * g + (row & 15);
  __hip_atomic_store(&M[(size_t)u * 8 + h * 4 + j], f2bf(v), __ATOMIC_RELAXED, AGENT);
}

__device__ __forceinline__ void st_f32x4(float* p, float v0, float v1, float v2, float v3) {
  ull lo = (ull)__float_as_uint(v0) | ((ull)__float_as_uint(v1) << 32);
  ull hi = (ull)__float_as_uint(v2) | ((ull)__float_as_uint(v3) << 32);
  __hip_atomic_store((ull*)p, lo, __ATOMIC_RELAXED, AGENT);
  __hip_atomic_store((ull*)(p + 2), hi, __ATOMIC_RELAXED, AGENT);
}

// arrive: __syncthreads drains this block's write-through stores, then
// write-once epoch to own padded 64B slot.
__device__ __forceinline__ void arrive(unsigned* sy, int blk, int tid, unsigned idx) {
  __syncthreads();
  if (tid == 0)
    __hip_atomic_store(&sy[16 * blk], idx, __ATOMIC_RELAXED, AGENT);
}

// wait on up to two block-ranges, then optional cadenced ACQUIRE.
__device__ __forceinline__ void wait2(unsigned* sy, int tid,
                                      int b0, int n0, unsigned t0,
                                      int b1, int n1, unsigned t1,
                                      bool acq, int blk) {
  int s = -1; unsigned tg = 0;
  if (tid < n0) { s = b0 + tid; tg = t0; }
  else if (tid < n0 + n1) { s = b1 + (tid - n0); tg = t1; }
  if (s >= 0)
    while (__hip_atomic_load(&sy[16 * s], __ATOMIC_RELAXED, AGENT) < tg)
      __builtin_amdgcn_s_sleep(1);
  __syncthreads();
  if (acq) {
    if (tid == 0) __hip_atomic_load(&sy[16 * blk], __ATOMIC_ACQUIRE, AGENT);
    __syncthreads();
  }
}

// N<=16 MFMA stage, A = [mA (SPLIT kts) | mB], B = NC weight cols in WL (LDS).
template<int NKT, int SPLIT, int NC>
__device__ __forceinline__ f32x4 stage_mm16(
    const ushortT* __restrict__ mA, const ushortT* __restrict__ mB,
    const ushortT* WL, float (*red)[64][4], int l, int w)
{
  const int mt = w & 3, kh = w >> 2;
  constexpr int H = NKT / 2;
  const int lo = kh * H;
  const int g = l >> 4, col = l & 15;
  f32x4 acc = {0.f, 0.f, 0.f, 0.f};
  short8 af[H];
  #pragma unroll
  for (int t = 0; t < H; ++t) {
    const int kt = lo + t;
    const ushortT* p = (kt < SPLIT)
        ? mA + (size_t)((kt * 4 + mt) * 64 + l) * 8
        : mB + (size_t)(((kt - SPLIT) * 4 + mt) * 64 + l) * 8;
    af[t] = *(const short8*)p;
  }
  #pragma unroll
  for (int t = 0; t < H; ++t) {
    short8 b = {0,0,0,0,0,0,0,0};
    if (col < NC)
      b = *(const short8*)(&WL[(size_t)(((lo + t) * 4 + g) * NC + col) * 8]);
    acc = __builtin_amdgcn_mfma_f32_16x16x32_bf16(af[t], b, acc, 0, 0, 0);
  }
  if (w >= 4) *(f32x4*)&red[w - 4][l][0] = acc;
  __syncthreads();
  if (w < 4) { f32x4 o = *(f32x4*)&red[w][l][0]; acc += o; }
  return acc;
}

// dual-gate stage: 32 weight cols (16 R + 16 Z), A loaded once, two accumulators.
template<int NKT, int SPLIT>
__device__ __forceinline__ void stage_gates(
    const ushortT* __restrict__ mA, const ushortT* __restrict__ mB,
    const ushortT* WL, float (*redR)[64][4], float (*redZ)[64][4],
    int l, int w, f32x4& accR, f32x4& accZ)
{
  const int mt = w & 3, kh = w >> 2;
  constexpr int H = NKT / 2;
  const int lo = kh * H;
  const int g = l >> 4, col = l & 15;
  accR = (f32x4){0.f, 0.f, 0.f, 0.f};
  accZ = (f32x4){0.f, 0.f, 0.f, 0.f};
  short8 af[H];
  #pragma unroll
  for (int t = 0; t < H; ++t) {
    const int kt = lo + t;
    const ushortT* p = (kt < SPLIT)
        ? mA + (size_t)((kt * 4 + mt) * 64 + l) * 8
        : mB + (size_t)(((kt - SPLIT) * 4 + mt) * 64 + l) * 8;
    af[t] = *(const short8*)p;
  }
  #pragma unroll
  for (int t = 0; t < H; ++t) {
    const int kt = lo + t;
    short8 bR = *(const short8*)(&WL[(size_t)((kt * 4 + g) * 32 + col) * 8]);
    short8 bZ = *(const short8*)(&WL[(size_t)((kt * 4 + g) * 32 + 16 + col) * 8]);
    accR = __builtin_amdgcn_mfma_f32_16x16x32_bf16(af[t], bR, accR, 0, 0, 0);
    accZ = __builtin_amdgcn_mfma_f32_16x16x32_bf16(af[t], bZ, accZ, 0, 0, 0);
  }
  if (w >= 4) {
    *(f32x4*)&redR[w - 4][l][0] = accR;
    *(f32x4*)&redZ[w - 4][l][0] = accZ;
  }
  __syncthreads();
  if (w < 4) {
    accR += *(f32x4*)&redR[w][l][0];
    accZ += *(f32x4*)&redZ[w][l][0];
  }
}

__device__ __forceinline__ float fold8(float v) {
  v += __shfl_xor(v, 8);
  v += __shfl_xor(v, 16);
  v += __shfl_xor(v, 32);
  return v;
}

// out = h1 @ Wout^T from the bf16 mirror; WLo kt-stride 36 (2-way banks, free).
__device__ __forceinline__ void out_dot(const ushortT* __restrict__ Mh1p,
                                        const ushortT* WLo, float bo,
                                        float* __restrict__ out,
                                        int s_store, int jo, int tid) {
  const int l = tid & 63, w = tid >> 6;
  const int rr = (w << 3) + (l & 7);
  const int ks = l >> 3;
  const int mt = rr >> 4, r15 = rr & 15;
  float a0 = 0.f;
  #pragma unroll
  for (int q = 0; q < 4; ++q) {
    const int kt = (ks << 2) + q;
    #pragma unroll
    for (int gg = 0; gg < 4; ++gg) {
      const int u = ((kt << 2) + mt) * 64 + (gg << 4) + r15;
      union { short8 v; ushortT us[8]; } M;
      M.v = *(const short8*)(Mh1p + (size_t)u * 8);
      ull wlo = *(const ull*)(WLo + kt * 36 + (gg << 2));
      ull whi = *(const ull*)(WLo + kt * 36 + 16 + (gg << 2));
      #pragma unroll
      for (int j = 0; j < 4; ++j) {
        float mv = __uint_as_float(((unsigned)M.us[j]) << 16);
        float wv = __uint_as_float((unsigned)((wlo >> (16 * j)) & 0xFFFFu) << 16);
        a0 = fmaf(mv, wv, a0);
      }
      #pragma unroll
      for (int j = 0; j < 4; ++j) {
        float mv = __uint_as_float(((unsigned)M.us[4 + j]) << 16);
        float wv = __uint_as_float((unsigned)((whi >> (16 * j)) & 0xFFFFu) << 16);
        a0 = fmaf(mv, wv, a0);
      }
    }
  }
  float v = fold8(a0);
  if ((l & 56) == 0)
    out[((size_t)s_store * BATCH + rr) * ODIM + jo] = v + bo;
}

// slot layout (R12/R14/R15). h/z col-major [1024][64] f32:
//   0 h0 | 262144 h1 | 524288 z0 | 786432 z1 | 1048576 Mh0 | 1179648 Mh1
//   1310720 Mrh0 | 1441792 Mrh1 | 1572864 Mx
// Roles (R16): A: blk<64 L0-gates(32c dual) | 64-127 candh1 h0n-half (reg partial)
//              | >=128 L1-gates(16c) + x-pack.
//           B: blk<64 candh0 | 64-127 candh1 rh1-half + update | >=128 out.
__global__ __launch_bounds__(NTHR, 2) void gru_pipe(
    const float* __restrict__ x,
    const float* __restrict__ Wr0, const float* __restrict__ br0,
    const float* __restrict__ Wz0, const float* __restrict__ bz0,
    const float* __restrict__ Wh0, const float* __restrict__ bh0,
    const float* __restrict__ Wr1, const float* __restrict__ br1,
    const float* __restrict__ Wz1, const float* __restrict__ bz1,
    const float* __restrict__ Wh1, const float* __restrict__ bh1,
    const float* __restrict__ Wout, const float* __restrict__ bout,
    float* __restrict__ out, char* __restrict__ ws, int nrot)
{
  __shared__ ushortT WSH[61440];     // 120 KB max (blk<64: 80K gates + 40K Wh0)
  __shared__ float redA[4][64][4];
  __shared__ float redB[4][64][4];

  const int blk = blockIdx.x;
  const int tid = threadIdx.x;
  const int l = tid & 63;
  const int w = tid >> 6;
  const int g = l >> 4;
  const int colL = l & 15;
  const int rowb = (w << 4) + (g << 2);

  unsigned* sy = (unsigned*)ws;                      // 16 KB: 256 epoch slots
  char* slots = ws + 16384;

  // ---- one-time weight staging (bf16, fragment order, LDS) ----
  if (blk < 64) {
    const int cb = blk * 16;
    for (int u = tid; u < 40 * 4 * 32; u += NTHR) {            // r0|z0, 32 cols
      int kt = u >> 7, gg = (u >> 5) & 3, c = u & 31;
      const float* src = (c < 16 ? Wr0 + (size_t)(cb + c) * 1280
                                 : Wz0 + (size_t)(cb + c - 16) * 1280) + kt * 32 + gg * 4;
      pack2(src, &WSH[(size_t)u * 8]);
    }
    for (int u = tid; u < 40 * 4 * 16; u += NTHR) {            // Wh0, 16 cols
      int kt = u >> 6, gg = (u >> 4) & 3, c = u & 15;
      pack2(Wh0 + (size_t)(cb + c) * 1280 + kt * 32 + gg * 4,
            &WSH[40960 + (size_t)u * 8]);
    }
  } else if (blk < 128) {
    const int cb = (blk - 64) * 16;
    for (int u = tid; u < 64 * 4 * 16; u += NTHR) {            // Wh1, 16 cols, full K
      int kt = u >> 6, gg = (u >> 4) & 3, c = u & 15;
      pack2(Wh1 + (size_t)(cb + c) * 2048 + kt * 32 + gg * 4, &WSH[(size_t)u * 8]);
    }
  } else {
    const int j1 = (blk - 128) * 8;
    for (int u = tid; u < 64 * 4 * 16; u += NTHR) {            // r1|z1, 8+8 cols
      int kt = u >> 6, gg = (u >> 4) & 3, c = u & 15;
      const float* src = (c < 8 ? Wr1 + (size_t)(j1 + c) * 2048
                                : Wz1 + (size_t)(j1 + c - 8) * 2048) + kt * 32 + gg * 4;
      pack2(src, &WSH[(size_t)u * 8]);
    }
    for (int u = tid; u < 256; u += NTHR) {                    // Wout col, stride 36
      float4 a = *(const float4*)(Wout + (size_t)(blk - 128) * HDIM + (u << 2));
      int kt = u >> 3, c4 = (u & 7) << 2;
      ushortT* dst = &WSH[32768 + kt * 36 + c4];
      dst[0] = f2bf(a.x); dst[1] = f2bf(a.y); dst[2] = f2bf(a.z); dst[3] = f2bf(a.w);
    }
  }
  // x(0) mirror -> Mx slot 0 (blocks >= 128, 16 units each), write-through
  if (blk >= 128 && tid < 16) {
    ushortT* Mx0 = (ushortT*)(slots + 1572864);
    int u = ((blk - 128) << 4) + tid;
    int kt = u >> 8, mtu = (u >> 6) & 3, lane = u & 63;
    int row = (mtu << 4) + (lane & 15), gg = lane >> 4;
    pack2a(x + (size_t)row * IDIM + (kt << 5) + (gg << 2), Mx0 + (size_t)u * 8);
  }

  // ---- per-thread constants ----
  float biasR = 0.f, biasZ = 0.f, biasA = 0.f, biasB = 0.f, bo = 0.f;
  int cgA = 0, cgB = 0;
  if (blk < 64) {
    cgA = blk * 16 + colL;            // gate cols (R and Z) and candh0 cols
    cgB = cgA;
    biasR = br0[cgA]; biasZ = bz0[cgA]; biasB = bh0[cgB];
  } else if (blk < 128) {
    cgB = (blk - 64) * 16 + colL;     // candh1 cols
    biasB = bh1[cgB];
  } else {
    cgA = ((blk - 128) << 3) + (colL & 7);
    biasA = (colL < 8) ? br1[cgA] : bz1[cgA];
    bo = bout[blk - 128];
  }

  // initial full barrier (weights + x(0) visible)
  arrive(sy, blk, tid, 1u);
  wait2(sy, tid, 0, 256, 1u, 0, 0, 0u, true, blk);

  for (int i = 0; i <= SLEN; ++i) {
    const int pc = i % nrot;
    const int pp = (i + nrot - 1) % nrot;
    const int pn = (i + 1) % nrot;
    char* Spc = slots + SLOTB * pc;
    char* Spp = slots + SLOTB * pp;

    const float* h0prev = (const float*)Spp;
    float*       h0cur  = (float*)Spc;
    const float* h1prev = (const float*)(Spp + 262144);
    float*       h1cur  = (float*)(Spc + 262144);
    float* z0f = (float*)(Spc + 524288);
    float* z1f = (float*)(Spc + 786432);
    const ushortT* Mh0p = (const ushortT*)(Spp + 1048576);
    ushortT*       Mh0w = (ushortT*)(Spc + 1048576);
    const ushortT* Mh1p = (const ushortT*)(Spp + 1179648);
    ushortT*       Mh1w = (ushortT*)(Spc + 1179648);
    ushortT* Mrh0 = (ushortT*)(Spc + 1310720);
    ushortT* Mrh1 = (ushortT*)(Spc + 1441792);
    const ushortT* MxP = (const ushortT*)(Spc + 1572864);
    ushortT*       MxW = (ushortT*)(slots + SLOTB * pn + 1572864);

    const unsigned eA = 2u * (unsigned)i + 2u;
    const unsigned eB = 2u * (unsigned)i + 3u;
    const bool acqA = (i % nrot) == 0;
    const bool acqB = ((i + 1) % nrot) == 0 || i == SLEN;

    f32x4 accP = {0.f, 0.f, 0.f, 0.f};   // candh1 h0n-half partial (blk 64-127)

    // ================= Phase A =================
    if (blk < 64) {
      if (i < SLEN) {
        float4 hq = {0.f, 0.f, 0.f, 0.f};
        if (w < 4) hq = *(const float4*)(h0prev + (size_t)cgA * 64 + rowb);
        f32x4 aR, aZ;
        stage_gates<40, 8>(MxP, Mh0p, WSH, redA, redB, l, w, aR, aZ);
        if (w < 4) {
          float sgR[4], sgZ[4];
          #pragma unroll
          for (int r = 0; r < 4; ++r) {
            sgR[r] = 1.f / (1.f + __expf(-(aR[r] + biasR)));
            sgZ[r] = 1.f / (1.f + __expf(-(aZ[r] + biasZ)));
          }
          mir_store(Mrh0, rowb + 0, cgA, sgR[0] * hq.x);
          mir_store(Mrh0, rowb + 1, cgA, sgR[1] * hq.y);
          mir_store(Mrh0, rowb + 2, cgA, sgR[2] * hq.z);
          mir_store(Mrh0, rowb + 3, cgA, sgR[3] * hq.w);
          st_f32x4(z0f + (size_t)cgA * 64 + rowb, sgZ[0], sgZ[1], sgZ[2], sgZ[3]);
        }
      }
    } else if (blk < 128) {
      if (i >= 1)   // candh1 h0n-half: kts 0-31 of Wh1, A = Mh0(i-1)
        accP = stage_mm16<32, 32, 16>(Mh0p, Mh0p, WSH, redA, l, w);
    } else {
      if (i + 1 < SLEN && tid < 16) {
        int u = ((blk - 128) << 4) + tid;
        int kt = u >> 8, mtu = (u >> 6) & 3, lane = u & 63;
        int row = (mtu << 4) + (lane & 15), gg = lane >> 4;
        pack2a(x + ((size_t)(i + 1) * BATCH + row) * IDIM + (kt << 5) + (gg << 2),
               MxW + (size_t)u * 8);
      }
      if (i >= 1) {
        float4 hq = {0.f, 0.f, 0.f, 0.f};
        if (w < 4 && colL < 8)
          hq = *(const float4*)(h1prev + (size_t)cgA * 64 + rowb);
        f32x4 acc = stage_mm16<64, 32, 16>(Mh0p, Mh1p, WSH, redA, l, w);
        if (w < 4) {
          float sg[4];
          #pragma unroll
          for (int r = 0; r < 4; ++r)
            sg[r] = 1.f / (1.f + __expf(-(acc[r] + biasA)));
          if (colL < 8) {
            mir_store(Mrh1, rowb + 0, cgA, sg[0] * hq.x);
            mir_store(Mrh1, rowb + 1, cgA, sg[1] * hq.y);
            mir_store(Mrh1, rowb + 2, cgA, sg[2] * hq.z);
            mir_store(Mrh1, rowb + 3, cgA, sg[3] * hq.w);
          } else {
            st_f32x4(z1f + (size_t)cgA * 64 + rowb, sg[0], sg[1], sg[2], sg[3]);
          }
        }
      }
    }
    arrive(sy, blk, tid, eA);
    // entering phase B: role-specific waits
    if (blk < 64)        wait2(sy, tid, 0, 64, eA, 0, 0, 0u, acqA, blk);
    else if (blk < 128)  wait2(sy, tid, 128, 128, eA, 0, 0, 0u, acqA, blk);
    else                 wait2(sy, tid, 0, 0, 0u, 0, 0, 0u, acqA, blk);

    // ================= Phase B =================
    if (blk < 64) {
      if (i < SLEN) {
        float4 zq = {0.f, 0.f, 0.f, 0.f}, hq = {0.f, 0.f, 0.f, 0.f};
        if (w < 4) {
          zq = *(const float4*)(z0f + (size_t)cgB * 64 + rowb);
          hq = *(const float4*)(h0prev + (size_t)cgB * 64 + rowb);
        }
        f32x4 acc = stage_mm16<40, 8, 16>(MxP, Mrh0, WSH + 40960, redA, l, w);
        if (w < 4) {
          float hn[4];
          const float hpv[4] = {hq.x, hq.y, hq.z, hq.w};
          const float zv[4] = {zq.x, zq.y, zq.z, zq.w};
          #pragma unroll
          for (int r = 0; r < 4; ++r) {
            float ht = tanhf(acc[r] + biasB);
            hn[r] = fmaf(zv[r], ht - hpv[r], hpv[r]);
            mir_store(Mh0w, rowb + r, cgB, hn[r]);
          }
          st_f32x4(h0cur + (size_t)cgB * 64 + rowb, hn[0], hn[1], hn[2], hn[3]);
        }
      }
    } else if (blk < 128) {
      if (i >= 1) {
        float4 zq = {0.f, 0.f, 0.f, 0.f}, hq = {0.f, 0.f, 0.f, 0.f};
        if (w < 4) {
          zq = *(const float4*)(z1f + (size_t)cgB * 64 + rowb);
          hq = *(const float4*)(h1prev + (size_t)cgB * 64 + rowb);
        }
        // rh1-half: kts 32-63 of Wh1 (WL base offset 32*4*16*8 = 16384 ushorts)
        f32x4 acc = stage_mm16<32, 0, 16>(Mrh1, Mrh1, WSH + 16384, redA, l, w);
        if (w < 4) {
          acc += accP;
          float hn[4];
          const float hpv[4] = {hq.x, hq.y, hq.z, hq.w};
          const float zv[4] = {zq.x, zq.y, zq.z, zq.w};
          #pragma unroll
          for (int r = 0; r < 4; ++r) {
            float ht = tanhf(acc[r] + biasB);
            hn[r] = fmaf(zv[r], ht - hpv[r], hpv[r]);
            mir_store(Mh1w, rowb + r, cgB, hn[r]);
          }
          st_f32x4(h1cur + (size_t)cgB * 64 + rowb, hn[0], hn[1], hn[2], hn[3]);
        }
      }
    } else {
      if (i >= 2)
        out_dot(Mh1p, WSH + 32768, bo, out, i - 2, blk - 128, tid);
    }
    arrive(sy, blk, tid, eB);
    // entering next iter's phase A: role-specific waits
    if (blk < 64)        wait2(sy, tid, 0, 64, eB, 128, 128, eA, acqB, blk);
    else if (blk < 128)  wait2(sy, tid, 0, 64, eB, 0, 0, 0u, acqB, blk);
    else                 wait2(sy, tid, 0, 128, eB, 0, 0, 0u, acqB, blk);
  }

  // ---- final full wait + acquire, then epilogue ----
  wait2(sy, tid, 0, 256, 2u * (unsigned)SLEN + 3u, 0, 0, 0u, true, blk);
  {
    char* Sf1 = slots + SLOTB * (SLEN % nrot);         // h1/Mh1 final
    char* Sf0 = slots + SLOTB * ((SLEN - 1) % nrot);   // h0 final
    if (blk >= 128)
      out_dot((const ushortT*)(Sf1 + 1179648), WSH + 32768, bo, out,
              SLEN - 1, blk - 128, tid);
    const float* h0fin = (const float*)Sf0;            // col-major
    const float* h1fin = (const float*)(Sf1 + 262144); // col-major
    const size_t base = (size_t)SLEN * BATCH * ODIM;
    const int u = blk * NTHR + tid;          // 0..131071
    float v;
    if (u < 65536) {
      int row = u >> 10, col = u & 1023;
      v = h0fin[(size_t)col * 64 + row];
    } else {
      int t = u - 65536;
      int row = t >> 10, col = t & 1023;
      v = h1fin[(size_t)col * 64 + row];
    }
    out[base + u] = v;
  }
}

extern "C" void kernel_launch(void* const* d_in, const int* in_sizes, int n_in,
                              void* d_out, int out_size, void* d_ws, size_t ws_size,
                              hipStream_t stream) {
  const float* xx  = (const float*)d_in[0];
  const float* Wr0 = (const float*)d_in[1];
  const float* br0 = (const float*)d_in[2];
  const float* Wz0 = (const float*)d_in[3];
  const float* bz0 = (const float*)d_in[4];
  const float* Wh0 = (const float*)d_in[5];
  const float* bh0 = (const float*)d_in[6];
  const float* Wr1 = (const float*)d_in[7];
  const float* br1 = (const float*)d_in[8];
  const float* Wz1 = (const float*)d_in[9];
  const float* bz1 = (const float*)d_in[10];
  const float* Wh1 = (const float*)d_in[11];
  const float* bh1 = (const float*)d_in[12];
  const float* Wou = (const float*)d_in[13];
  const float* bou = (const float*)d_in[14];

  // rotation depth from ws_size; min 4 (WAW transitivity needs >=3)
  long long avail = (long long)ws_size - 16384;
  int nrot = (int)(avail / (long long)SLOTB);
  if (nrot > 16) nrot = 16;
  if (nrot < 4) nrot = 4;

  hipMemsetAsync(d_ws, 0, 16384 + (size_t)nrot * SLOTB, stream);

  gru_pipe<<<dim3(NBLK), dim3(NTHR), 0, stream>>>(
      xx, Wr0, br0, Wz0, bz0, Wh0, bh0,
      Wr1, br1, Wz1, bz1, Wh1, bh1, Wou, bou,
      (float*)d_out, (char*)d_ws, nrot);
}

// Round 17
// 6627.258 us; speedup vs baseline: 1.6876x; 1.6876x over previous
//
#include <hip/hip_runtime.h>

#define SLEN 512
#define BATCH 64
#define IDIM 256
#define HDIM 1024
#define ODIM 128
#define NBLK 256
#define NTHR 512
#define AGENT __HIP_MEMORY_SCOPE_AGENT
#define SLOTB 1605632ull   // bytes per rotation slot

typedef unsigned short ushortT;
typedef unsigned long long ull;
typedef __attribute__((ext_vector_type(8))) short short8;
typedef __attribute__((ext_vector_type(4))) float f32x4;

__device__ __forceinline__ ushortT f2bf(float f) {
  unsigned u = __float_as_uint(f);
  unsigned r = (u + 0x7FFFu + ((u >> 16) & 1u)) >> 16;
  return (ushortT)r;
}

// pack A/B fragment halves into LDS (weights): src[0..3]->e0..3, src[16..19]->e4..7
__device__ __forceinline__ void pack2(const float* __restrict__ s, ushortT* d) {
  float4 a = *(const float4*)s;
  float4 b = *(const float4*)(s + 16);
  short8 v;
  v[0]=(short)f2bf(a.x); v[1]=(short)f2bf(a.y); v[2]=(short)f2bf(a.z); v[3]=(short)f2bf(a.w);
  v[4]=(short)f2bf(b.x); v[5]=(short)f2bf(b.y); v[6]=(short)f2bf(b.z); v[7]=(short)f2bf(b.w);
  *(short8*)d = v;
}

// write-through (agent, sc-bypass) variant for cross-block global mirrors
__device__ __forceinline__ void pack2a(const float* __restrict__ s, ushortT* d) {
  float4 a = *(const float4*)s;
  float4 b = *(const float4*)(s + 16);
  ull lo = (ull)f2bf(a.x) | ((ull)f2bf(a.y) << 16) | ((ull)f2bf(a.z) << 32) | ((ull)f2bf(a.w) << 48);
  ull hi = (ull)f2bf(b.x) | ((ull)f2bf(b.y) << 16) | ((ull)f2bf(b.z) << 32) | ((ull)f2bf(b.w) << 48);
  __hip_atomic_store((ull*)d, lo, __ATOMIC_RELAXED, AGENT);
  __hip_atomic_store((ull*)(d + 4), hi, __ATOMIC_RELAXED, AGENT);
}

// write-through store of one f32 into fragment-ordered bf16 mirror at (row, cL)
__device__ __forceinline__ void mir_store(ushortT* M, int row, int cL, float v) {
  int kt = cL >> 5, c5 = cL & 31;
  int h = c5 >> 4, g = (c5 >> 2) & 3, j = c5 & 3;
  int u = ((kt * 4 + (row >> 4)) * 64) + 16 * g + (row & 15);
  __hip_atomic_store(&M[(size_t)u * 8 + h * 4 + j], f2bf(v), __ATOMIC_RELAXED, AGENT);
}

// write-through 16B (two 8B) store of 4 consecutive f32 (col-major h/z)
__device__ __forceinline__ void st_f32x4(float* p, float v0, float v1, float v2, float v3) {
  ull lo = (ull)__float_as_uint(v0) | ((ull)__float_as_uint(v1) << 32);
  ull hi = (ull)__float_as_uint(v2) | ((ull)__float_as_uint(v3) << 32);
  __hip_atomic_store((ull*)p, lo, __ATOMIC_RELAXED, AGENT);
  __hip_atomic_store((ull*)(p + 2), hi, __ATOMIC_RELAXED, AGENT);
}

// arrive: drain block's write-through stores (__syncthreads retires vmcnt),
// then write-once epoch to own padded 64B slot.
__device__ __forceinline__ void arrive(unsigned* sy, int blk, int tid, unsigned idx) {
  __syncthreads();
  if (tid == 0)
    __hip_atomic_store(&sy[16 * blk], idx, __ATOMIC_RELAXED, AGENT);
}

// wait on up to two block-ranges (possibly different target epochs), then
// optional cadenced ACQUIRE (L2 refresh across slot rotation).
__device__ __forceinline__ void wait2(unsigned* sy, int tid,
                                      int b0, int n0, unsigned t0,
                                      int b1, int n1, unsigned t1,
                                      bool acq, int blk) {
  int s = -1; unsigned tg = 0;
  if (tid < n0) { s = b0 + tid; tg = t0; }
  else if (tid < n0 + n1) { s = b1 + (tid - n0); tg = t1; }
  if (s >= 0)
    while (__hip_atomic_load(&sy[16 * s], __ATOMIC_RELAXED, AGENT) < tg)
      __builtin_amdgcn_s_sleep(1);
  __syncthreads();
  if (acq) {
    if (tid == 0) __hip_atomic_load(&sy[16 * blk], __ATOMIC_ACQUIRE, AGENT);
    __syncthreads();
  }
}

// N<=16 MFMA stage, A = [mA (SPLIT kts) | mB], B = NC weight cols in WL (LDS).
template<int NKT, int SPLIT, int NC>
__device__ __forceinline__ f32x4 stage_mm16(
    const ushortT* __restrict__ mA, const ushortT* __restrict__ mB,
    const ushortT* WL, float (*red)[64][4], int l, int w)
{
  const int mt = w & 3, kh = w >> 2;
  constexpr int H = NKT / 2;
  const int lo = kh * H;
  const int g = l >> 4, col = l & 15;
  f32x4 acc = {0.f, 0.f, 0.f, 0.f};
  short8 af[H];
  #pragma unroll
  for (int t = 0; t < H; ++t) {
    const int kt = lo + t;
    const ushortT* p = (kt < SPLIT)
        ? mA + (size_t)((kt * 4 + mt) * 64 + l) * 8
        : mB + (size_t)(((kt - SPLIT) * 4 + mt) * 64 + l) * 8;
    af[t] = *(const short8*)p;
  }
  #pragma unroll
  for (int t = 0; t < H; ++t) {
    short8 b = {0,0,0,0,0,0,0,0};
    if (col < NC)
      b = *(const short8*)(&WL[(size_t)(((lo + t) * 4 + g) * NC + col) * 8]);
    acc = __builtin_amdgcn_mfma_f32_16x16x32_bf16(af[t], b, acc, 0, 0, 0);
  }
  if (w >= 4) *(f32x4*)&red[w - 4][l][0] = acc;
  __syncthreads();
  if (w < 4) { f32x4 o = *(f32x4*)&red[w][l][0]; acc += o; }
  return acc;
}

__device__ __forceinline__ float fold8(float v) {
  v += __shfl_xor(v, 8);
  v += __shfl_xor(v, 16);
  v += __shfl_xor(v, 32);
  return v;
}

// out = h1 @ Wout^T from the bf16 mirror; WLo kt-stride 36 (2-way banks, free).
__device__ __forceinline__ void out_dot(const ushortT* __restrict__ Mh1p,
                                        const ushortT* WLo, float bo,
                                        float* __restrict__ out,
                                        int s_store, int jo, int tid) {
  const int l = tid & 63, w = tid >> 6;
  const int rr = (w << 3) + (l & 7);
  const int ks = l >> 3;
  const int mt = rr >> 4, r15 = rr & 15;
  float a0 = 0.f;
  #pragma unroll
  for (int q = 0; q < 4; ++q) {
    const int kt = (ks << 2) + q;
    #pragma unroll
    for (int gg = 0; gg < 4; ++gg) {
      const int u = ((kt << 2) + mt) * 64 + (gg << 4) + r15;
      union { short8 v; ushortT us[8]; } M;
      M.v = *(const short8*)(Mh1p + (size_t)u * 8);
      ull wlo = *(const ull*)(WLo + kt * 36 + (gg << 2));
      ull whi = *(const ull*)(WLo + kt * 36 + 16 + (gg << 2));
      #pragma unroll
      for (int j = 0; j < 4; ++j) {
        float mv = __uint_as_float(((unsigned)M.us[j]) << 16);
        float wv = __uint_as_float((unsigned)((wlo >> (16 * j)) & 0xFFFFu) << 16);
        a0 = fmaf(mv, wv, a0);
      }
      #pragma unroll
      for (int j = 0; j < 4; ++j) {
        float mv = __uint_as_float(((unsigned)M.us[4 + j]) << 16);
        float wv = __uint_as_float((unsigned)((whi >> (16 * j)) & 0xFFFFu) << 16);
        a0 = fmaf(mv, wv, a0);
      }
    }
  }
  float v = fold8(a0);
  if ((l & 56) == 0)
    out[((size_t)s_store * BATCH + rr) * ODIM + jo] = v + bo;
}

// slot layout (R12/R14). h/z col-major [1024][64] f32:
//   0 h0 | 262144 h1 | 524288 z0 | 786432 z1 | 1048576 Mh0 | 1179648 Mh1
//   1310720 Mrh0 | 1441792 Mrh1 | 1572864 Mx
__global__ __launch_bounds__(NTHR, 2) void gru_pipe(
    const float* __restrict__ x,
    const float* __restrict__ Wr0, const float* __restrict__ br0,
    const float* __restrict__ Wz0, const float* __restrict__ bz0,
    const float* __restrict__ Wh0, const float* __restrict__ bh0,
    const float* __restrict__ Wr1, const float* __restrict__ br1,
    const float* __restrict__ Wz1, const float* __restrict__ bz1,
    const float* __restrict__ Wh1, const float* __restrict__ bh1,
    const float* __restrict__ Wout, const float* __restrict__ bout,
    float* __restrict__ out, char* __restrict__ ws, int nrot)
{
  __shared__ ushortT WSH[53248];     // 104 KB: WA | WB
  __shared__ float red[4][64][4];

  const int blk = blockIdx.x;
  const int tid = threadIdx.x;
  const int l = tid & 63;
  const int w = tid >> 6;
  const int g = l >> 4;
  const int colL = l & 15;
  const int rowb = (w << 4) + (g << 2);

  unsigned* sy = (unsigned*)ws;                      // 16 KB: 256 epoch slots
  char* slots = ws + 16384;

  ushortT* WA = WSH;
  ushortT* WB = WSH + (blk < 128 ? 20480 : 32768);

  // ---- one-time weight staging (bf16, fragment order, LDS) ----
  if (blk < 128) {
    const int j0 = blk * 8;
    for (int u = tid; u < 40 * 4 * 16; u += NTHR) {
      int kt = u >> 6, gg = (u >> 4) & 3, c = u & 15;
      const float* src = (c < 8 ? Wr0 + (size_t)(j0 + c) * 1280
                                : Wz0 + (size_t)(j0 + c - 8) * 1280) + kt * 32 + gg * 4;
      pack2(src, &WA[(size_t)u * 8]);
    }
  } else {
    const int j1 = (blk - 128) * 8;
    for (int u = tid; u < 64 * 4 * 16; u += NTHR) {
      int kt = u >> 6, gg = (u >> 4) & 3, c = u & 15;
      const float* src = (c < 8 ? Wr1 + (size_t)(j1 + c) * 2048
                                : Wz1 + (size_t)(j1 + c - 8) * 2048) + kt * 32 + gg * 4;
      pack2(src, &WA[(size_t)u * 8]);
    }
  }
  if (blk < 64) {
    const int c0 = blk * 16;
    for (int u = tid; u < 40 * 4 * 16; u += NTHR) {
      int kt = u >> 6, gg = (u >> 4) & 3, c = u & 15;
      pack2(Wh0 + (size_t)(c0 + c) * 1280 + kt * 32 + gg * 4, &WB[(size_t)u * 8]);
    }
  } else if (blk < 128) {
    const int c0 = (blk - 64) * 16;
    for (int u = tid; u < 64 * 4 * 16; u += NTHR) {
      int kt = u >> 6, gg = (u >> 4) & 3, c = u & 15;
      pack2(Wh1 + (size_t)(c0 + c) * 2048 + kt * 32 + gg * 4, &WB[(size_t)u * 8]);
    }
  } else {
    for (int u = tid; u < 256; u += NTHR) {
      float4 a = *(const float4*)(Wout + (size_t)(blk - 128) * HDIM + (u << 2));
      int kt = u >> 3, c4 = (u & 7) << 2;
      ushortT* dst = &WB[kt * 36 + c4];
      dst[0] = f2bf(a.x); dst[1] = f2bf(a.y); dst[2] = f2bf(a.z); dst[3] = f2bf(a.w);
    }
  }
  // x(0) mirror -> Mx slot 0 (blocks >= 128, 16 units each), write-through
  if (blk >= 128 && tid < 16) {
    ushortT* Mx0 = (ushortT*)(slots + 1572864);
    int u = ((blk - 128) << 4) + tid;
    int kt = u >> 8, mtu = (u >> 6) & 3, lane = u & 63;
    int row = (mtu << 4) + (lane & 15), gg = lane >> 4;
    pack2a(x + (size_t)row * IDIM + (kt << 5) + (gg << 2), Mx0 + (size_t)u * 8);
  }

  // ---- per-thread constants ----
  float biasA = 0.f, biasB = 0.f, bo = 0.f;
  int cgA = 0, cgB = 0;
  if (blk < 128) {
    cgA = (blk << 3) + (colL & 7);
    biasA = (colL < 8) ? br0[cgA] : bz0[cgA];
  } else {
    cgA = ((blk - 128) << 3) + (colL & 7);
    biasA = (colL < 8) ? br1[cgA] : bz1[cgA];
  }
  if (blk < 64)       { cgB = (blk << 4) + colL;        biasB = bh0[cgB]; }
  else if (blk < 128) { cgB = ((blk - 64) << 4) + colL; biasB = bh1[cgB]; }
  else                { bo = bout[blk - 128]; }

  // initial full barrier (weights + x(0) visible)
  arrive(sy, blk, tid, 1u);
  wait2(sy, tid, 0, 256, 1u, 0, 0, 0u, true, blk);

  for (int i = 0; i <= SLEN; ++i) {
    const int pc = i % nrot;
    const int pp = (i + nrot - 1) % nrot;
    const int pn = (i + 1) % nrot;
    char* Spc = slots + SLOTB * pc;
    char* Spp = slots + SLOTB * pp;

    const float* h0prev = (const float*)Spp;
    float*       h0cur  = (float*)Spc;
    const float* h1prev = (const float*)(Spp + 262144);
    float*       h1cur  = (float*)(Spc + 262144);
    float* z0f = (float*)(Spc + 524288);
    float* z1f = (float*)(Spc + 786432);
    const ushortT* Mh0p = (const ushortT*)(Spp + 1048576);
    ushortT*       Mh0w = (ushortT*)(Spc + 1048576);
    const ushortT* Mh1p = (const ushortT*)(Spp + 1179648);
    ushortT*       Mh1w = (ushortT*)(Spc + 1179648);
    ushortT* Mrh0 = (ushortT*)(Spc + 1310720);
    ushortT* Mrh1 = (ushortT*)(Spc + 1441792);
    const ushortT* MxP = (const ushortT*)(Spc + 1572864);
    ushortT*       MxW = (ushortT*)(slots + SLOTB * pn + 1572864);

    const unsigned eA = 2u * (unsigned)i + 2u;   // this iter's A epoch
    const unsigned eB = 2u * (unsigned)i + 3u;   // this iter's B epoch
    const bool acqA = (i % nrot) == 0;
    const bool acqB = ((i + 1) % nrot) == 0 || i == SLEN;

    // ================= Phase A: gates (+ x-pack on blk>=128) =================
    if (blk < 128) {
      if (i < SLEN) {
        float4 hq = {0.f, 0.f, 0.f, 0.f};
        if (w < 4 && colL < 8)
          hq = *(const float4*)(h0prev + (size_t)cgA * 64 + rowb);
        f32x4 acc = stage_mm16<40, 8, 16>(MxP, Mh0p, WA, red, l, w);
        if (w < 4) {
          float sg[4];
          #pragma unroll
          for (int r = 0; r < 4; ++r)
            sg[r] = 1.f / (1.f + __expf(-(acc[r] + biasA)));
          if (colL < 8) {
            mir_store(Mrh0, rowb + 0, cgA, sg[0] * hq.x);
            mir_store(Mrh0, rowb + 1, cgA, sg[1] * hq.y);
            mir_store(Mrh0, rowb + 2, cgA, sg[2] * hq.z);
            mir_store(Mrh0, rowb + 3, cgA, sg[3] * hq.w);
          } else {
            st_f32x4(z0f + (size_t)cgA * 64 + rowb, sg[0], sg[1], sg[2], sg[3]);
          }
        }
      }
    } else {
      // x-pack for step i+1 (in phase A: keeps out_dot off L0's chain)
      if (i + 1 < SLEN && tid < 16) {
        int u = ((blk - 128) << 4) + tid;
        int kt = u >> 8, mtu = (u >> 6) & 3, lane = u & 63;
        int row = (mtu << 4) + (lane & 15), gg = lane >> 4;
        pack2a(x + ((size_t)(i + 1) * BATCH + row) * IDIM + (kt << 5) + (gg << 2),
               MxW + (size_t)u * 8);
      }
      if (i >= 1) {
        float4 hq = {0.f, 0.f, 0.f, 0.f};
        if (w < 4 && colL < 8)
          hq = *(const float4*)(h1prev + (size_t)cgA * 64 + rowb);
        f32x4 acc = stage_mm16<64, 32, 16>(Mh0p, Mh1p, WA, red, l, w);
        if (w < 4) {
          float sg[4];
          #pragma unroll
          for (int r = 0; r < 4; ++r)
            sg[r] = 1.f / (1.f + __expf(-(acc[r] + biasA)));
          if (colL < 8) {
            mir_store(Mrh1, rowb + 0, cgA, sg[0] * hq.x);
            mir_store(Mrh1, rowb + 1, cgA, sg[1] * hq.y);
            mir_store(Mrh1, rowb + 2, cgA, sg[2] * hq.z);
            mir_store(Mrh1, rowb + 3, cgA, sg[3] * hq.w);
          } else {
            st_f32x4(z1f + (size_t)cgA * 64 + rowb, sg[0], sg[1], sg[2], sg[3]);
          }
        }
      }
    }
    arrive(sy, blk, tid, eA);
    // entering phase B: role-specific waits
    if (blk < 64)        wait2(sy, tid, 0, 128, eA, 0, 0, 0u, acqA, blk);
    else if (blk < 128)  wait2(sy, tid, 128, 128, eA, 0, 0, 0u, acqA, blk);
    else                 wait2(sy, tid, 0, 0, 0u, 0, 0, 0u, acqA, blk);

    // ================= Phase B: candidates + out =================
    if (blk < 64) {
      if (i < SLEN) {
        float4 zq = {0.f, 0.f, 0.f, 0.f}, hq = {0.f, 0.f, 0.f, 0.f};
        if (w < 4) {
          zq = *(const float4*)(z0f + (size_t)cgB * 64 + rowb);
          hq = *(const float4*)(h0prev + (size_t)cgB * 64 + rowb);
        }
        f32x4 acc = stage_mm16<40, 8, 16>(MxP, Mrh0, WB, red, l, w);
        if (w < 4) {
          float hn[4];
          const float hpv[4] = {hq.x, hq.y, hq.z, hq.w};
          const float zv[4] = {zq.x, zq.y, zq.z, zq.w};
          #pragma unroll
          for (int r = 0; r < 4; ++r) {
            float ht = tanhf(acc[r] + biasB);
            hn[r] = fmaf(zv[r], ht - hpv[r], hpv[r]);
            mir_store(Mh0w, rowb + r, cgB, hn[r]);
          }
          st_f32x4(h0cur + (size_t)cgB * 64 + rowb, hn[0], hn[1], hn[2], hn[3]);
        }
      }
    } else if (blk < 128) {
      if (i >= 1) {
        float4 zq = {0.f, 0.f, 0.f, 0.f}, hq = {0.f, 0.f, 0.f, 0.f};
        if (w < 4) {
          zq = *(const float4*)(z1f + (size_t)cgB * 64 + rowb);
          hq = *(const float4*)(h1prev + (size_t)cgB * 64 + rowb);
        }
        f32x4 acc = stage_mm16<64, 32, 16>(Mh0p, Mrh1, WB, red, l, w);
        if (w < 4) {
          float hn[4];
          const float hpv[4] = {hq.x, hq.y, hq.z, hq.w};
          const float zv[4] = {zq.x, zq.y, zq.z, zq.w};
          #pragma unroll
          for (int r = 0; r < 4; ++r) {
            float ht = tanhf(acc[r] + biasB);
            hn[r] = fmaf(zv[r], ht - hpv[r], hpv[r]);
            mir_store(Mh1w, rowb + r, cgB, hn[r]);
          }
          st_f32x4(h1cur + (size_t)cgB * 64 + rowb, hn[0], hn[1], hn[2], hn[3]);
        }
      }
    } else {
      if (i >= 2)
        out_dot(Mh1p, WB, bo, out, i - 2, blk - 128, tid);
    }
    arrive(sy, blk, tid, eB);
    // entering next iter's phase A: role-specific waits
    if (blk < 128) wait2(sy, tid, 0, 64, eB, 128, 128, eA, acqB, blk);
    else           wait2(sy, tid, 0, 128, eB, 0, 0, 0u, acqB, blk);
  }

  // ---- final full wait + acquire, then epilogue ----
  wait2(sy, tid, 0, 256, 2u * (unsigned)SLEN + 3u, 0, 0, 0u, true, blk);
  {
    char* Sf1 = slots + SLOTB * (SLEN % nrot);         // h1 final, Mh1 final
    char* Sf0 = slots + SLOTB * ((SLEN - 1) % nrot);   // h0 final
    if (blk >= 128)
      out_dot((const ushortT*)(Sf1 + 1179648), WB, bo, out, SLEN - 1, blk - 128, tid);
    const float* h0fin = (const float*)Sf0;            // col-major
    const float* h1fin = (const float*)(Sf1 + 262144); // col-major
    const size_t base = (size_t)SLEN * BATCH * ODIM;
    const int u = blk * NTHR + tid;          // 0..131071
    float v;
    if (u < 65536) {
      int row = u >> 10, col = u & 1023;
      v = h0fin[(size_t)col * 64 + row];
    } else {
      int t = u - 65536;
      int row = t >> 10, col = t & 1023;
      v = h1fin[(size_t)col * 64 + row];
    }
    out[base + u] = v;
  }
}

extern "C" void kernel_launch(void* const* d_in, const int* in_sizes, int n_in,
                              void* d_out, int out_size, void* d_ws, size_t ws_size,
                              hipStream_t stream) {
  const float* xx  = (const float*)d_in[0];
  const float* Wr0 = (const float*)d_in[1];
  const float* br0 = (const float*)d_in[2];
  const float* Wz0 = (const float*)d_in[3];
  const float* bz0 = (const float*)d_in[4];
  const float* Wh0 = (const float*)d_in[5];
  const float* bh0 = (const float*)d_in[6];
  const float* Wr1 = (const float*)d_in[7];
  const float* br1 = (const float*)d_in[8];
  const float* Wz1 = (const float*)d_in[9];
  const float* bz1 = (const float*)d_in[10];
  const float* Wh1 = (const float*)d_in[11];
  const float* bh1 = (const float*)d_in[12];
  const float* Wou = (const float*)d_in[13];
  const float* bou = (const float*)d_in[14];

  long long avail = (long long)ws_size - 16384;
  int nrot = (int)(avail / (long long)SLOTB);
  if (nrot > 16) nrot = 16;
  if (nrot < 2) nrot = 2;

  hipMemsetAsync(d_ws, 0, 16384 + (size_t)nrot * SLOTB, stream);

  gru_pipe<<<dim3(NBLK), dim3(NTHR), 0, stream>>>(
      xx, Wr0, br0, Wz0, bz0, Wh0, bh0,
      Wr1, br1, Wz1, bz1, Wh1, bh1, Wou, bou,
      (float*)d_out, (char*)d_ws, nrot);
}